// Round 2
// baseline (258.161 us; speedup 1.0000x reference)
//
#include <hip/hip_runtime.h>

// RBFN fused: out = sqrt(1 + max(|x|^2+|c|^2-2 x.c, 0)) @ W
// R6 (resubmit — R1 bench was GPUAcquisitionTimeout, no data):
//  (a) bf16 packing: hand-rolled RNE bit-trick (~7 VALU insts / 2 vals)
//      -> v_cvt_pk_bf16_f32 inline asm (1 inst). ~14 packs/chunk/thread.
//  (b) reduce_ws kernel folded into rbf_fused behind a hand-rolled
//      device-scope grid barrier (512 blocks @ 2/CU needed, 3/CU LDS
//      capacity -> co-resident), removing the 2nd dispatch + inter-kernel
//      drain (~54us of wall) and reading the 33.5MB partials L3-warm.
//  Counter at ws+WS_ELEMS, memset each launch (graph node, poison-proof).
// Fallback MODE 1 (memset + atomicAdd) kept for small ws.

typedef __attribute__((ext_vector_type(8))) short bf16x8;
typedef __attribute__((ext_vector_type(4))) float f32x4;
typedef __attribute__((ext_vector_type(2))) float f32x2;
typedef __attribute__((ext_vector_type(2))) unsigned int u32x2;
typedef __attribute__((ext_vector_type(4))) unsigned int u32x4;

#define N_FEAT 128
#define L_OUT  64
#define LDK    136   // sStage row stride (shorts), 272B
#define LDC    40    // sPhi/sWT row stride (shorts), 80B
#define NSB    16    // centre splits: 32 row-blocks x 16 = 512 blocks = 2/CU
#define NCH    16    // 32-centre chunks per block
#define NBLK   (32 * NSB)
#define OUT_ELEMS ((size_t)8192 * L_OUT)
#define WS_ELEMS  ((size_t)NSB * OUT_ELEMS)

__device__ __forceinline__ unsigned int pk2(float a, float b) {
    // dst.lo = bf16(a), dst.hi = bf16(b), RNE — same rounding as the old
    // bit-trick, 1 VALU inst instead of ~7. No builtin on gfx950 (T12).
    unsigned int r;
    asm("v_cvt_pk_bf16_f32 %0, %1, %2" : "=v"(r) : "v"(a), "v"(b));
    return r;
}

// MODE 0: write partials to ws, grid-barrier, in-kernel reduce -> out.
// MODE 1: atomicAdd into out (fallback).
template <int MODE>
__global__ __launch_bounds__(512, 4) void rbf_fused(
    const float* __restrict__ xs, const float* __restrict__ centre,
    const float* __restrict__ weight, float* __restrict__ ws,
    float* __restrict__ out) {

    __shared__ __align__(16) unsigned short sStage[2][32][LDK];
    __shared__ __align__(16) unsigned short sWT[2][L_OUT][LDC];
    __shared__ __align__(16) unsigned short sPhi[256][LDC];   // 8 waves x 32 rows
    __shared__ float sC2[2][32];

    const int tid  = threadIdx.x;
    const int w    = tid >> 6;        // 0..7
    const int lane = tid & 63;
    const int quad = lane >> 4;
    const int n16  = lane & 15;

    const int mb = blockIdx.x >> 4;
    const int sb = blockIdx.x & (NSB - 1);
    const int rowBase = mb * 256;
    const int chunk0  = sb * NCH;

    // ---- x fragments: direct global->register (B-operand layout), + |x|^2
    bf16x8 aF[2][4];
    float  x2v[2];
    #pragma unroll
    for (int xt = 0; xt < 2; ++xt) {
        const float* xr = xs + (size_t)(rowBase + 32 * w + xt * 16 + n16) * N_FEAT
                             + quad * 8;
        float ss = 0.f;
        #pragma unroll
        for (int kc = 0; kc < 4; ++kc) {
            f32x4 a = *(const f32x4*)(xr + kc * 32);
            f32x4 b = *(const f32x4*)(xr + kc * 32 + 4);
            ss += a.x*a.x + a.y*a.y + a.z*a.z + a.w*a.w
                + b.x*b.x + b.y*b.y + b.z*b.z + b.w*b.w;
            u32x4 p = { pk2(-2.f*a.x, -2.f*a.y), pk2(-2.f*a.z, -2.f*a.w),
                        pk2(-2.f*b.x, -2.f*b.y), pk2(-2.f*b.z, -2.f*b.w) };
            aF[xt][kc] = __builtin_bit_cast(bf16x8, p);
        }
        ss += __shfl_xor(ss, 16);
        ss += __shfl_xor(ss, 32);
        x2v[xt] = ss;
    }

    f32x4 oAcc[2][4];
    #pragma unroll
    for (int xt = 0; xt < 2; ++xt)
        #pragma unroll
        for (int lt = 0; lt < 4; ++lt)
            oAcc[xt][lt] = (f32x4){0.f, 0.f, 0.f, 0.f};

    // staging roles (512 threads)
    const int sr  = tid >> 4;          // centre row 0..31
    const int sq  = tid & 15;          // 8-float group
    const int wl  = tid & 63;          // W: output col l
    const int wc0 = (tid >> 6) * 4;    // W: 4 centre rows

    f32x4 pc[2];     // prefetched centre piece (8 floats)
    float pw[4];     // prefetched W column piece

    auto loadChunk = [&](int c) {
        const float* g = centre + (size_t)(c * 32 + sr) * N_FEAT + sq * 8;
        pc[0] = *(const f32x4*)(g);
        pc[1] = *(const f32x4*)(g + 4);
        const float* gw = weight + (size_t)(c * 32 + wc0) * L_OUT + wl;
        #pragma unroll
        for (int i = 0; i < 4; ++i) pw[i] = gw[i * L_OUT];
    };
    auto storeChunk = [&](int b) {
        float ss = pc[0].x*pc[0].x + pc[0].y*pc[0].y + pc[0].z*pc[0].z + pc[0].w*pc[0].w
                 + pc[1].x*pc[1].x + pc[1].y*pc[1].y + pc[1].z*pc[1].z + pc[1].w*pc[1].w;
        u32x4 p = { pk2(pc[0].x, pc[0].y), pk2(pc[0].z, pc[0].w),
                    pk2(pc[1].x, pc[1].y), pk2(pc[1].z, pc[1].w) };
        *(u32x4*)&sStage[b][sr][sq * 8] = p;
        ss += __shfl_xor(ss, 1);
        ss += __shfl_xor(ss, 2);
        ss += __shfl_xor(ss, 4);
        ss += __shfl_xor(ss, 8);
        if (sq == 0) sC2[b][sr] = ss + 1.0f;
        u32x2 pwp = { pk2(pw[0], pw[1]), pk2(pw[2], pw[3]) };
        *(u32x2*)&sWT[b][wl][wc0] = pwp;
    };

    loadChunk(chunk0);
    storeChunk(0);
    __syncthreads();

    for (int ic = 0; ic < NCH; ++ic) {
        const int cur = ic & 1;
        if (ic < NCH - 1) loadChunk(chunk0 + ic + 1);

        // GEMM1 (S^T: m=centre, n=x) + phi -> sPhi (wave-private strip)
        #pragma unroll
        for (int ct = 0; ct < 2; ++ct) {
            f32x4 sAcc[2];
            #pragma unroll
            for (int xt = 0; xt < 2; ++xt) sAcc[xt] = (f32x4){0.f, 0.f, 0.f, 0.f};
            #pragma unroll
            for (int kc = 0; kc < 4; ++kc) {
                bf16x8 cA = *(const bf16x8*)&sStage[cur][ct * 16 + n16][kc * 32 + quad * 8];
                #pragma unroll
                for (int xt = 0; xt < 2; ++xt)
                    sAcc[xt] = __builtin_amdgcn_mfma_f32_16x16x32_bf16(
                        cA, aF[xt][kc], sAcc[xt], 0, 0, 0);
            }
            f32x4 c2p1 = *(const f32x4*)&sC2[cur][ct * 16 + quad * 4];
            #pragma unroll
            for (int xt = 0; xt < 2; ++xt) {
                float base[4];
                #pragma unroll
                for (int r = 0; r < 4; ++r) base[r] = x2v[xt] + c2p1[r];
                float ph[4];
                #pragma unroll
                for (int r = 0; r < 4; ++r) {
                    float t = sAcc[xt][r] + base[r];
                    ph[r] = __builtin_amdgcn_sqrtf(fmaxf(t, 1.0f));
                }
                u32x2 pk = { pk2(ph[0], ph[1]), pk2(ph[2], ph[3]) };
                *(u32x2*)&sPhi[32 * w + xt * 16 + n16][ct * 16 + quad * 4] = pk;
            }
        }

        // GEMM2: oAcc += phi @ W
        bf16x8 pF[2];
        #pragma unroll
        for (int xt = 0; xt < 2; ++xt)
            pF[xt] = *(const bf16x8*)&sPhi[32 * w + xt * 16 + n16][quad * 8];
        #pragma unroll
        for (int lt = 0; lt < 4; ++lt) {
            bf16x8 wF = *(const bf16x8*)&sWT[cur][lt * 16 + n16][quad * 8];
            #pragma unroll
            for (int xt = 0; xt < 2; ++xt)
                oAcc[xt][lt] = __builtin_amdgcn_mfma_f32_16x16x32_bf16(
                    pF[xt], wF, oAcc[xt][lt], 0, 0, 0);
        }

        if (ic < NCH - 1) {
            storeChunk(cur ^ 1);
            __syncthreads();
        }
    }

    // ---- epilogue
    if (MODE == 0) {
        float* ob = ws + ((size_t)sb * 8192 + rowBase + 32 * w) * L_OUT;
        #pragma unroll
        for (int xt = 0; xt < 2; ++xt)
            #pragma unroll
            for (int lt = 0; lt < 4; ++lt)
                #pragma unroll
                for (int r = 0; r < 4; ++r)
                    ob[(xt * 16 + quad * 4 + r) * L_OUT + lt * 16 + n16] =
                        oAcc[xt][lt][r];

        // ---- device-scope grid barrier (all 512 blocks co-resident:
        // need 2/CU, LDS caps at 3/CU, VGPR<=128 enforced by launch_bounds)
        unsigned int* cnt = (unsigned int*)(ws + WS_ELEMS);
        __syncthreads();                    // all waves: vmcnt(0) -> stores in L2
        if (tid == 0) {
            __threadfence();                // release: L2 writeback (cross-XCD vis)
            __hip_atomic_fetch_add(cnt, 1u, __ATOMIC_RELEASE,
                                   __HIP_MEMORY_SCOPE_AGENT);
            while (__hip_atomic_load(cnt, __ATOMIC_ACQUIRE,
                                     __HIP_MEMORY_SCOPE_AGENT) < (unsigned)NBLK)
                __builtin_amdgcn_s_sleep(2);
        }
        __syncthreads();
        __threadfence();                    // acquire: invalidate L1/L2

        // ---- phase 2: reduce 16 partial slices (L3-warm) -> out
        const size_t gid = (size_t)blockIdx.x * 512 + tid;   // 262144 threads
        const float* wp = ws + gid * 2;
        float a0 = 0.f, a1 = 0.f;
        #pragma unroll
        for (int sbi = 0; sbi < NSB; ++sbi) {
            f32x2 v = *(const f32x2*)(wp + (size_t)sbi * OUT_ELEMS);
            a0 += v.x; a1 += v.y;
        }
        *(f32x2*)(out + gid * 2) = (f32x2){a0, a1};
    } else {
        float* ob = out + (size_t)(rowBase + 32 * w) * L_OUT;
        #pragma unroll
        for (int xt = 0; xt < 2; ++xt)
            #pragma unroll
            for (int lt = 0; lt < 4; ++lt)
                #pragma unroll
                for (int r = 0; r < 4; ++r)
                    atomicAdd(&ob[(xt * 16 + quad * 4 + r) * L_OUT + lt * 16 + n16],
                              oAcc[xt][lt][r]);
    }
}

extern "C" void kernel_launch(void* const* d_in, const int* in_sizes, int n_in,
                              void* d_out, int out_size, void* d_ws, size_t ws_size,
                              hipStream_t stream) {
    (void)in_sizes; (void)n_in; (void)out_size;
    const float* xs     = (const float*)d_in[0];
    const float* centre = (const float*)d_in[1];
    const float* weight = (const float*)d_in[2];
    float* out = (float*)d_out;

    if (ws_size >= (WS_ELEMS + 16) * sizeof(float)) {
        float* ws = (float*)d_ws;
        hipMemsetAsync(ws + WS_ELEMS, 0, sizeof(unsigned int), stream);
        rbf_fused<0><<<dim3(NBLK), dim3(512), 0, stream>>>(xs, centre, weight, ws, out);
    } else {
        hipMemsetAsync(d_out, 0, OUT_ELEMS * sizeof(float), stream);
        rbf_fused<1><<<dim3(NBLK), dim3(512), 0, stream>>>(xs, centre, weight,
                                                           (float*)d_ws, out);
    }
}

// Round 7
// 135.743 us; speedup vs baseline: 1.9018x; 1.9018x over previous
//
#include <hip/hip_runtime.h>

// RBFN fused: out = sqrt(1 + max(|x|^2+|c|^2-2 x.c, 0)) @ W
// R8 (resubmit — R6 bench was GPUAcquisitionTimeout, no data):
// spin-free single-dispatch. R7's grid barrier (unbounded relaxed spin)
// is a hang risk if agent-relaxed loads don't bypass the non-coherent
// per-XCD L2. Replace with last-arriver-reduces: 32 counters (one per
// output row-block mb); each block fetch_adds cnt[mb] with RELEASE (one
// buffer_wbl2 = the mandatory partials writeback to MALL); the 16th
// arriver acquire-fences once and reduces its 256x64 chunk (1MB MALL-read,
// ~8us, 32 reducers in parallel). NO polling anywhere -> cannot deadlock;
// worst failure mode is absmax, not a hang. pk2 via v_cvt_pk_bf16_f32
// kept (-32% VALU, measured R6).
// Fallback MODE 1 (memset + atomicAdd) kept for small ws.

typedef __attribute__((ext_vector_type(8))) short bf16x8;
typedef __attribute__((ext_vector_type(4))) float f32x4;
typedef __attribute__((ext_vector_type(2))) unsigned int u32x2;
typedef __attribute__((ext_vector_type(4))) unsigned int u32x4;

#define N_FEAT 128
#define L_OUT  64
#define LDK    136   // sStage row stride (shorts), 272B
#define LDC    40    // sPhi/sWT row stride (shorts), 80B
#define NSB    16    // centre splits: 32 row-blocks x 16 = 512 blocks = 2/CU
#define NCH    16    // 32-centre chunks per block
#define NMB    32    // output row-blocks (256 rows each)
#define NBLK   (NMB * NSB)
#define OUT_ELEMS ((size_t)8192 * L_OUT)
#define WS_ELEMS  ((size_t)NSB * OUT_ELEMS)

__device__ __forceinline__ unsigned int pk2(float a, float b) {
    // dst.lo = bf16(a), dst.hi = bf16(b), RNE — 1 VALU inst (T12).
    unsigned int r;
    asm("v_cvt_pk_bf16_f32 %0, %1, %2" : "=v"(r) : "v"(a), "v"(b));
    return r;
}

// MODE 0: partials to ws; last arriver per mb reduces -> out. MODE 1: atomicAdd.
template <int MODE>
__global__ __launch_bounds__(512, 4) void rbf_fused(
    const float* __restrict__ xs, const float* __restrict__ centre,
    const float* __restrict__ weight, float* __restrict__ ws,
    float* __restrict__ out) {

    __shared__ __align__(16) unsigned short sStage[2][32][LDK];
    __shared__ __align__(16) unsigned short sWT[2][L_OUT][LDC];
    __shared__ __align__(16) unsigned short sPhi[256][LDC];   // 8 waves x 32 rows
    __shared__ float sC2[2][32];
    __shared__ int sRed;

    const int tid  = threadIdx.x;
    const int w    = tid >> 6;        // 0..7
    const int lane = tid & 63;
    const int quad = lane >> 4;
    const int n16  = lane & 15;

    const int mb = blockIdx.x >> 4;
    const int sb = blockIdx.x & (NSB - 1);
    const int rowBase = mb * 256;
    const int chunk0  = sb * NCH;

    // ---- x fragments: direct global->register (B-operand layout), + |x|^2
    bf16x8 aF[2][4];
    float  x2v[2];
    #pragma unroll
    for (int xt = 0; xt < 2; ++xt) {
        const float* xr = xs + (size_t)(rowBase + 32 * w + xt * 16 + n16) * N_FEAT
                             + quad * 8;
        float ss = 0.f;
        #pragma unroll
        for (int kc = 0; kc < 4; ++kc) {
            f32x4 a = *(const f32x4*)(xr + kc * 32);
            f32x4 b = *(const f32x4*)(xr + kc * 32 + 4);
            ss += a.x*a.x + a.y*a.y + a.z*a.z + a.w*a.w
                + b.x*b.x + b.y*b.y + b.z*b.z + b.w*b.w;
            u32x4 p = { pk2(-2.f*a.x, -2.f*a.y), pk2(-2.f*a.z, -2.f*a.w),
                        pk2(-2.f*b.x, -2.f*b.y), pk2(-2.f*b.z, -2.f*b.w) };
            aF[xt][kc] = __builtin_bit_cast(bf16x8, p);
        }
        ss += __shfl_xor(ss, 16);
        ss += __shfl_xor(ss, 32);
        x2v[xt] = ss;
    }

    f32x4 oAcc[2][4];
    #pragma unroll
    for (int xt = 0; xt < 2; ++xt)
        #pragma unroll
        for (int lt = 0; lt < 4; ++lt)
            oAcc[xt][lt] = (f32x4){0.f, 0.f, 0.f, 0.f};

    // staging roles (512 threads)
    const int sr  = tid >> 4;          // centre row 0..31
    const int sq  = tid & 15;          // 8-float group
    const int wl  = tid & 63;          // W: output col l
    const int wc0 = (tid >> 6) * 4;    // W: 4 centre rows

    f32x4 pc[2];     // prefetched centre piece (8 floats)
    float pw[4];     // prefetched W column piece

    auto loadChunk = [&](int c) {
        const float* g = centre + (size_t)(c * 32 + sr) * N_FEAT + sq * 8;
        pc[0] = *(const f32x4*)(g);
        pc[1] = *(const f32x4*)(g + 4);
        const float* gw = weight + (size_t)(c * 32 + wc0) * L_OUT + wl;
        #pragma unroll
        for (int i = 0; i < 4; ++i) pw[i] = gw[i * L_OUT];
    };
    auto storeChunk = [&](int b) {
        float ss = pc[0].x*pc[0].x + pc[0].y*pc[0].y + pc[0].z*pc[0].z + pc[0].w*pc[0].w
                 + pc[1].x*pc[1].x + pc[1].y*pc[1].y + pc[1].z*pc[1].z + pc[1].w*pc[1].w;
        u32x4 p = { pk2(pc[0].x, pc[0].y), pk2(pc[0].z, pc[0].w),
                    pk2(pc[1].x, pc[1].y), pk2(pc[1].z, pc[1].w) };
        *(u32x4*)&sStage[b][sr][sq * 8] = p;
        ss += __shfl_xor(ss, 1);
        ss += __shfl_xor(ss, 2);
        ss += __shfl_xor(ss, 4);
        ss += __shfl_xor(ss, 8);
        if (sq == 0) sC2[b][sr] = ss + 1.0f;
        u32x2 pwp = { pk2(pw[0], pw[1]), pk2(pw[2], pw[3]) };
        *(u32x2*)&sWT[b][wl][wc0] = pwp;
    };

    loadChunk(chunk0);
    storeChunk(0);
    __syncthreads();

    for (int ic = 0; ic < NCH; ++ic) {
        const int cur = ic & 1;
        if (ic < NCH - 1) loadChunk(chunk0 + ic + 1);

        // GEMM1 (S^T: m=centre, n=x) + phi -> sPhi (wave-private strip)
        #pragma unroll
        for (int ct = 0; ct < 2; ++ct) {
            f32x4 sAcc[2];
            #pragma unroll
            for (int xt = 0; xt < 2; ++xt) sAcc[xt] = (f32x4){0.f, 0.f, 0.f, 0.f};
            #pragma unroll
            for (int kc = 0; kc < 4; ++kc) {
                bf16x8 cA = *(const bf16x8*)&sStage[cur][ct * 16 + n16][kc * 32 + quad * 8];
                #pragma unroll
                for (int xt = 0; xt < 2; ++xt)
                    sAcc[xt] = __builtin_amdgcn_mfma_f32_16x16x32_bf16(
                        cA, aF[xt][kc], sAcc[xt], 0, 0, 0);
            }
            f32x4 c2p1 = *(const f32x4*)&sC2[cur][ct * 16 + quad * 4];
            #pragma unroll
            for (int xt = 0; xt < 2; ++xt) {
                float ph[4];
                #pragma unroll
                for (int r = 0; r < 4; ++r) {
                    float t = sAcc[xt][r] + x2v[xt] + c2p1[r];
                    ph[r] = __builtin_amdgcn_sqrtf(fmaxf(t, 1.0f));
                }
                u32x2 pk = { pk2(ph[0], ph[1]), pk2(ph[2], ph[3]) };
                *(u32x2*)&sPhi[32 * w + xt * 16 + n16][ct * 16 + quad * 4] = pk;
            }
        }

        // GEMM2: oAcc += phi @ W
        bf16x8 pF[2];
        #pragma unroll
        for (int xt = 0; xt < 2; ++xt)
            pF[xt] = *(const bf16x8*)&sPhi[32 * w + xt * 16 + n16][quad * 8];
        #pragma unroll
        for (int lt = 0; lt < 4; ++lt) {
            bf16x8 wF = *(const bf16x8*)&sWT[cur][lt * 16 + n16][quad * 8];
            #pragma unroll
            for (int xt = 0; xt < 2; ++xt)
                oAcc[xt][lt] = __builtin_amdgcn_mfma_f32_16x16x32_bf16(
                    pF[xt], wF, oAcc[xt][lt], 0, 0, 0);
        }

        if (ic < NCH - 1) {
            storeChunk(cur ^ 1);
            __syncthreads();
        }
    }

    // ---- epilogue
    if (MODE == 0) {
        float* ob = ws + ((size_t)sb * 8192 + rowBase + 32 * w) * L_OUT;
        #pragma unroll
        for (int xt = 0; xt < 2; ++xt)
            #pragma unroll
            for (int lt = 0; lt < 4; ++lt)
                #pragma unroll
                for (int r = 0; r < 4; ++r)
                    ob[(xt * 16 + quad * 4 + r) * L_OUT + lt * 16 + n16] =
                        oAcc[xt][lt][r];

        // ---- last-arriver-per-mb reduction (spin-free, cannot hang).
        // Release on the arrival RMW = one buffer_wbl2/block (partials ->
        // MALL). The 16th arriver for this mb acquire-fences once
        // (invalidate local caches) and reduces its 256x64 chunk from the
        // 16 slices — 1MB MALL-resident read per reducer, 32 reducers in
        // parallel. No ordered polling, no per-thread fences (R6 lesson).
        unsigned int* cnt = (unsigned int*)(ws + WS_ELEMS);
        __syncthreads();                    // all waves vmcnt(0): stores in L2
        if (tid == 0) {
            unsigned int old = __hip_atomic_fetch_add(
                &cnt[mb], 1u, __ATOMIC_RELEASE, __HIP_MEMORY_SCOPE_AGENT);
            sRed = (old == (unsigned)(NSB - 1));
        }
        __syncthreads();

        if (sRed) {                          // block-uniform branch
            if (tid == 0)
                __builtin_amdgcn_fence(__ATOMIC_ACQUIRE, "agent");
            __syncthreads();
            // reduce rows [mb*256, mb*256+256) x 64 cols = 16384 floats
            const size_t rowOff = (size_t)mb * 256 * L_OUT;
            #pragma unroll
            for (int rep = 0; rep < 8; ++rep) {
                const size_t idx = rowOff + (size_t)rep * 2048 + (size_t)tid * 4;
                f32x4 s = (f32x4){0.f, 0.f, 0.f, 0.f};
                #pragma unroll
                for (int sbi = 0; sbi < NSB; ++sbi)
                    s += *(const f32x4*)(ws + (size_t)sbi * OUT_ELEMS + idx);
                *(f32x4*)(out + idx) = s;
            }
        }
    } else {
        float* ob = out + (size_t)(rowBase + 32 * w) * L_OUT;
        #pragma unroll
        for (int xt = 0; xt < 2; ++xt)
            #pragma unroll
            for (int lt = 0; lt < 4; ++lt)
                #pragma unroll
                for (int r = 0; r < 4; ++r)
                    atomicAdd(&ob[(xt * 16 + quad * 4 + r) * L_OUT + lt * 16 + n16],
                              oAcc[xt][lt][r]);
    }
}

extern "C" void kernel_launch(void* const* d_in, const int* in_sizes, int n_in,
                              void* d_out, int out_size, void* d_ws, size_t ws_size,
                              hipStream_t stream) {
    (void)in_sizes; (void)n_in; (void)out_size;
    const float* xs     = (const float*)d_in[0];
    const float* centre = (const float*)d_in[1];
    const float* weight = (const float*)d_in[2];
    float* out = (float*)d_out;

    if (ws_size >= (WS_ELEMS + NMB) * sizeof(float)) {
        float* ws = (float*)d_ws;
        hipMemsetAsync(ws + WS_ELEMS, 0, NMB * sizeof(unsigned int), stream);
        rbf_fused<0><<<dim3(NBLK), dim3(512), 0, stream>>>(xs, centre, weight, ws, out);
    } else {
        hipMemsetAsync(d_out, 0, OUT_ELEMS * sizeof(float), stream);
        rbf_fused<1><<<dim3(NBLK), dim3(512), 0, stream>>>(xs, centre, weight,
                                                           (float*)d_ws, out);
    }
}

// Round 8
// 102.386 us; speedup vs baseline: 2.5215x; 1.3258x over previous
//
#include <hip/hip_runtime.h>

// RBFN fused: out = sqrt(1 + max(|x|^2+|c|^2-2 x.c, 0)) @ W
// R9: REVERT to the two-dispatch R5 structure + keep pk2 asm.
// Evidence: wall - dispatch is a ~53us CONSTANT (R5 54.4 / R6 52.2 /
// R8 53.3) => the separate reduce_ws kernel cost ~1us (L2-resident), and
// R8's in-kernel last-arriver reduction ADDED ~28us (32-block tail on
// fence-invalidated partials). Fusing the reduction was a net loss; the
// only validated win is pk2 via v_cvt_pk_bf16_f32 (-35% VALU cycles,
// measured R6 and R8).
// Structure: R5 (512 blocks x 512 thr, NSB=16 split-K over centres,
// partials to ws, separate 2048-block reduce_ws) + pk2 asm.

typedef __attribute__((ext_vector_type(8))) short bf16x8;
typedef __attribute__((ext_vector_type(4))) float f32x4;
typedef __attribute__((ext_vector_type(2))) unsigned int u32x2;
typedef __attribute__((ext_vector_type(4))) unsigned int u32x4;

#define N_FEAT 128
#define L_OUT  64
#define LDK    136   // sStage row stride (shorts), 272B
#define LDC    40    // sPhi/sWT row stride (shorts), 80B
#define NSB    16    // centre splits: 32 row-blocks x 16 = 512 blocks = 2/CU
#define NCH    16    // 32-centre chunks per block
#define WS_ELEMS ((size_t)NSB * 8192 * L_OUT)

__device__ __forceinline__ unsigned int pk2(float a, float b) {
    // dst.lo = bf16(a), dst.hi = bf16(b), RNE — 1 VALU inst instead of ~7
    // (no builtin on gfx950; T12). Validated R6/R8: VALU cycles -35%.
    unsigned int r;
    asm("v_cvt_pk_bf16_f32 %0, %1, %2" : "=v"(r) : "v"(a), "v"(b));
    return r;
}

// MODE 0: write partials to ws. MODE 1: atomicAdd into out (fallback).
template <int MODE>
__global__ __launch_bounds__(512, 4) void rbf_fused(
    const float* __restrict__ xs, const float* __restrict__ centre,
    const float* __restrict__ weight, float* __restrict__ dst) {

    __shared__ __align__(16) unsigned short sStage[2][32][LDK];
    __shared__ __align__(16) unsigned short sWT[2][L_OUT][LDC];
    __shared__ __align__(16) unsigned short sPhi[256][LDC];   // 8 waves x 32 rows
    __shared__ float sC2[2][32];

    const int tid  = threadIdx.x;
    const int w    = tid >> 6;        // 0..7
    const int lane = tid & 63;
    const int quad = lane >> 4;
    const int n16  = lane & 15;

    const int mb = blockIdx.x >> 4;
    const int sb = blockIdx.x & (NSB - 1);
    const int rowBase = mb * 256;
    const int chunk0  = sb * NCH;

    // ---- x fragments: direct global->register (B-operand layout), + |x|^2
    bf16x8 aF[2][4];
    float  x2v[2];
    #pragma unroll
    for (int xt = 0; xt < 2; ++xt) {
        const float* xr = xs + (size_t)(rowBase + 32 * w + xt * 16 + n16) * N_FEAT
                             + quad * 8;
        float ss = 0.f;
        #pragma unroll
        for (int kc = 0; kc < 4; ++kc) {
            f32x4 a = *(const f32x4*)(xr + kc * 32);
            f32x4 b = *(const f32x4*)(xr + kc * 32 + 4);
            ss += a.x*a.x + a.y*a.y + a.z*a.z + a.w*a.w
                + b.x*b.x + b.y*b.y + b.z*b.z + b.w*b.w;
            u32x4 p = { pk2(-2.f*a.x, -2.f*a.y), pk2(-2.f*a.z, -2.f*a.w),
                        pk2(-2.f*b.x, -2.f*b.y), pk2(-2.f*b.z, -2.f*b.w) };
            aF[xt][kc] = __builtin_bit_cast(bf16x8, p);
        }
        ss += __shfl_xor(ss, 16);
        ss += __shfl_xor(ss, 32);
        x2v[xt] = ss;
    }

    f32x4 oAcc[2][4];
    #pragma unroll
    for (int xt = 0; xt < 2; ++xt)
        #pragma unroll
        for (int lt = 0; lt < 4; ++lt)
            oAcc[xt][lt] = (f32x4){0.f, 0.f, 0.f, 0.f};

    // staging roles (512 threads)
    const int sr  = tid >> 4;          // centre row 0..31
    const int sq  = tid & 15;          // 8-float group
    const int wl  = tid & 63;          // W: output col l
    const int wc0 = (tid >> 6) * 4;    // W: 4 centre rows

    f32x4 pc[2];     // prefetched centre piece (8 floats)
    float pw[4];     // prefetched W column piece

    auto loadChunk = [&](int c) {
        const float* g = centre + (size_t)(c * 32 + sr) * N_FEAT + sq * 8;
        pc[0] = *(const f32x4*)(g);
        pc[1] = *(const f32x4*)(g + 4);
        const float* gw = weight + (size_t)(c * 32 + wc0) * L_OUT + wl;
        #pragma unroll
        for (int i = 0; i < 4; ++i) pw[i] = gw[i * L_OUT];
    };
    auto storeChunk = [&](int b) {
        float ss = pc[0].x*pc[0].x + pc[0].y*pc[0].y + pc[0].z*pc[0].z + pc[0].w*pc[0].w
                 + pc[1].x*pc[1].x + pc[1].y*pc[1].y + pc[1].z*pc[1].z + pc[1].w*pc[1].w;
        u32x4 p = { pk2(pc[0].x, pc[0].y), pk2(pc[0].z, pc[0].w),
                    pk2(pc[1].x, pc[1].y), pk2(pc[1].z, pc[1].w) };
        *(u32x4*)&sStage[b][sr][sq * 8] = p;
        ss += __shfl_xor(ss, 1);
        ss += __shfl_xor(ss, 2);
        ss += __shfl_xor(ss, 4);
        ss += __shfl_xor(ss, 8);
        if (sq == 0) sC2[b][sr] = ss + 1.0f;
        u32x2 pwp = { pk2(pw[0], pw[1]), pk2(pw[2], pw[3]) };
        *(u32x2*)&sWT[b][wl][wc0] = pwp;
    };

    loadChunk(chunk0);
    storeChunk(0);
    __syncthreads();

    for (int ic = 0; ic < NCH; ++ic) {
        const int cur = ic & 1;
        if (ic < NCH - 1) loadChunk(chunk0 + ic + 1);

        // GEMM1 (S^T: m=centre, n=x) + phi -> sPhi (wave-private strip)
        #pragma unroll
        for (int ct = 0; ct < 2; ++ct) {
            f32x4 sAcc[2];
            #pragma unroll
            for (int xt = 0; xt < 2; ++xt) sAcc[xt] = (f32x4){0.f, 0.f, 0.f, 0.f};
            #pragma unroll
            for (int kc = 0; kc < 4; ++kc) {
                bf16x8 cA = *(const bf16x8*)&sStage[cur][ct * 16 + n16][kc * 32 + quad * 8];
                #pragma unroll
                for (int xt = 0; xt < 2; ++xt)
                    sAcc[xt] = __builtin_amdgcn_mfma_f32_16x16x32_bf16(
                        cA, aF[xt][kc], sAcc[xt], 0, 0, 0);
            }
            f32x4 c2p1 = *(const f32x4*)&sC2[cur][ct * 16 + quad * 4];
            #pragma unroll
            for (int xt = 0; xt < 2; ++xt) {
                float ph[4];
                #pragma unroll
                for (int r = 0; r < 4; ++r) {
                    float t = sAcc[xt][r] + x2v[xt] + c2p1[r];
                    ph[r] = __builtin_amdgcn_sqrtf(fmaxf(t, 1.0f));
                }
                u32x2 pk = { pk2(ph[0], ph[1]), pk2(ph[2], ph[3]) };
                *(u32x2*)&sPhi[32 * w + xt * 16 + n16][ct * 16 + quad * 4] = pk;
            }
        }

        // GEMM2: oAcc += phi @ W
        bf16x8 pF[2];
        #pragma unroll
        for (int xt = 0; xt < 2; ++xt)
            pF[xt] = *(const bf16x8*)&sPhi[32 * w + xt * 16 + n16][quad * 8];
        #pragma unroll
        for (int lt = 0; lt < 4; ++lt) {
            bf16x8 wF = *(const bf16x8*)&sWT[cur][lt * 16 + n16][quad * 8];
            #pragma unroll
            for (int xt = 0; xt < 2; ++xt)
                oAcc[xt][lt] = __builtin_amdgcn_mfma_f32_16x16x32_bf16(
                    pF[xt], wF, oAcc[xt][lt], 0, 0, 0);
        }

        if (ic < NCH - 1) {
            storeChunk(cur ^ 1);
            __syncthreads();
        }
    }

    // ---- epilogue
    if (MODE == 0) {
        float* ob = dst + ((size_t)sb * 8192 + rowBase + 32 * w) * L_OUT;
        #pragma unroll
        for (int xt = 0; xt < 2; ++xt)
            #pragma unroll
            for (int lt = 0; lt < 4; ++lt)
                #pragma unroll
                for (int r = 0; r < 4; ++r)
                    ob[(xt * 16 + quad * 4 + r) * L_OUT + lt * 16 + n16] =
                        oAcc[xt][lt][r];
    } else {
        float* ob = dst + (size_t)(rowBase + 32 * w) * L_OUT;
        #pragma unroll
        for (int xt = 0; xt < 2; ++xt)
            #pragma unroll
            for (int lt = 0; lt < 4; ++lt)
                #pragma unroll
                for (int r = 0; r < 4; ++r)
                    atomicAdd(&ob[(xt * 16 + quad * 4 + r) * L_OUT + lt * 16 + n16],
                              oAcc[xt][lt][r]);
    }
}

__global__ __launch_bounds__(256) void reduce_ws(const float* __restrict__ ws,
                                                float* __restrict__ out) {
    const size_t i = ((size_t)blockIdx.x * 256 + threadIdx.x) * 4;
    f32x4 s = (f32x4){0.f, 0.f, 0.f, 0.f};
    #pragma unroll
    for (int sb = 0; sb < NSB; ++sb)
        s += *(const f32x4*)(ws + (size_t)sb * 8192 * L_OUT + i);
    *(f32x4*)(out + i) = s;
}

extern "C" void kernel_launch(void* const* d_in, const int* in_sizes, int n_in,
                              void* d_out, int out_size, void* d_ws, size_t ws_size,
                              hipStream_t stream) {
    (void)in_sizes; (void)n_in; (void)out_size;
    const float* xs     = (const float*)d_in[0];
    const float* centre = (const float*)d_in[1];
    const float* weight = (const float*)d_in[2];
    float* out = (float*)d_out;

    if (ws_size >= WS_ELEMS * sizeof(float)) {
        float* ws = (float*)d_ws;
        rbf_fused<0><<<dim3(32 * NSB), dim3(512), 0, stream>>>(xs, centre, weight, ws);
        reduce_ws<<<dim3(8192 * L_OUT / 4 / 256), dim3(256), 0, stream>>>(ws, out);
    } else {
        hipMemsetAsync(d_out, 0, (size_t)8192 * L_OUT * sizeof(float), stream);
        rbf_fused<1><<<dim3(32 * NSB), dim3(512), 0, stream>>>(xs, centre, weight, out);
    }
}